// Round 1
// baseline (196.855 us; speedup 1.0000x reference)
//
#include <hip/hip_runtime.h>

// out[b*Lp + p, c, k] = x[b, c, p + k]
// B=128, C=4, L=2048, K=200, Lp=1849
// Output elements: 128*1849*4*200 = 189,337,600 (f32, ~757 MB) -> write-bound.

#define B_  128
#define C_  4
#define L_  2048
#define K_  200
#define LP_ 1849
#define K4_ (K_ / 4)   // 50 float4 per row

__global__ __launch_bounds__(256) void unfold_kernel(
    const float* __restrict__ x, float* __restrict__ out, unsigned int total4)
{
    unsigned int tid    = blockIdx.x * blockDim.x + threadIdx.x;
    unsigned int stride = gridDim.x * blockDim.x;

    for (unsigned int q = tid; q < total4; q += stride) {
        // q indexes output float4s: q = (((b*LP + p)*C + c)*K4 + k4)
        unsigned int k4   = q % K4_;
        unsigned int rem  = q / K4_;          // (b*LP + p)*C + c
        unsigned int c    = rem % C_;
        unsigned int rem2 = rem / C_;         // b*LP + p
        unsigned int p    = rem2 % LP_;
        unsigned int b    = rem2 / LP_;

        const float* src = x + ((size_t)(b * C_ + c) * L_ + p + k4 * 4);
        float4 v = make_float4(src[0], src[1], src[2], src[3]);
        reinterpret_cast<float4*>(out)[q] = v;
    }
}

extern "C" void kernel_launch(void* const* d_in, const int* in_sizes, int n_in,
                              void* d_out, int out_size, void* d_ws, size_t ws_size,
                              hipStream_t stream)
{
    const float* x = (const float*)d_in[0];
    float* out = (float*)d_out;

    unsigned int total4 = (unsigned int)(out_size / 4);  // 47,334,400
    int block = 256;
    int grid = 16384;
    unfold_kernel<<<grid, block, 0, stream>>>(x, out, total4);
}

// Round 2
// 149.964 us; speedup vs baseline: 1.3127x; 1.3127x over previous
//
#include <hip/hip_runtime.h>

// out[b*Lp + p, c, k] = x[b, c, p + k]
// B=128, C=4, L=2048, K=200, Lp=1849 (= 43*43, so TP=43 tiles perfectly)
// 757 MB written (write-bound). Strategy: stage x tile in LDS (reads are 4MB
// total, reused ~200x), then emit pure coalesced float4 stores -> 1 VMEM
// instr per 1KB wave-store, same profile as memset (which hits 6.5 TB/s).

#define B_   128
#define C_   4
#define L_   2048
#define K_   200
#define LP_  1849
#define TP_  43                 // p-rows per block; 43*43 = 1849 exactly, no tail
#define SPAN_ (TP_ - 1 + K_)    // 242 floats staged per channel
#define CHS_  274               // channel stride in LDS: 242 + 242/8 + pad
#define N4_  (TP_ * 200)        // 8600 float4s written per block

__global__ __launch_bounds__(256) void unfold_lds(const float* __restrict__ x,
                                                  float* __restrict__ out)
{
    __shared__ float lds[C_ * CHS_];   // ~4.4 KB

    unsigned int blk = blockIdx.x;
    unsigned int b   = blk / 43u;
    unsigned int t   = blk - b * 43u;
    unsigned int p0  = t * TP_;

    // Stage x[b, c, p0 .. p0+241] for all 4 channels, with +1/8 swizzle pad
    // (i -> i + (i>>3)) so the stride-4 read pattern below spreads banks.
    for (unsigned int idx = threadIdx.x; idx < C_ * SPAN_; idx += 256u) {
        unsigned int c = idx / SPAN_;
        unsigned int i = idx - c * SPAN_;
        float v = x[(b * C_ + c) * L_ + p0 + i];
        lds[c * CHS_ + i + (i >> 3)] = v;
    }
    __syncthreads();

    // Block's output region is one contiguous chunk of TP*800 floats.
    float4* out4 = reinterpret_cast<float4*>(out) + (size_t)(b * LP_ + p0) * 200u;

    for (unsigned int i = threadIdx.x; i < N4_; i += 256u) {
        unsigned int p  = i / 200u;          // local p row
        unsigned int r  = i - p * 200u;
        unsigned int c  = r / 50u;
        unsigned int k4 = r - c * 50u;
        unsigned int a0 = p + 4u * k4;       // x offset within channel
        unsigned int a1 = a0 + 1u, a2 = a0 + 2u, a3 = a0 + 3u;
        const float* base = lds + c * CHS_;
        float4 v;
        v.x = base[a0 + (a0 >> 3)];
        v.y = base[a1 + (a1 >> 3)];
        v.z = base[a2 + (a2 >> 3)];
        v.w = base[a3 + (a3 >> 3)];
        out4[i] = v;
    }
}

extern "C" void kernel_launch(void* const* d_in, const int* in_sizes, int n_in,
                              void* d_out, int out_size, void* d_ws, size_t ws_size,
                              hipStream_t stream)
{
    const float* x = (const float*)d_in[0];
    float* out = (float*)d_out;

    int grid = B_ * 43;   // 5504 blocks, each writes 137.6 KB contiguous
    unfold_lds<<<grid, 256, 0, stream>>>(x, out);
}

// Round 3
// 149.106 us; speedup vs baseline: 1.3202x; 1.0058x over previous
//
#include <hip/hip_runtime.h>

// out[b*Lp + p, c, k] = x[b, c, p + k]
// B=128, C=4, L=2048, K=200, Lp=1849. 757 MB written -> write-bound.
// Strategy: 4 phase-shifted LDS copies of the x tile so every output float4
// is ONE aligned ds_read_b128 + ONE global_store_dwordx4. Copy phi, slot m
// holds x[p0 + phi + 4m .. +3]; output (p,c,k4) reads phi=p&3, m=(p>>2)+k4.

#define B_     128
#define C_     4
#define L_     2048
#define K_     200
#define LP_    1849
#define TP_    32              // p-rows per full tile
#define NT_    58              // 57 full tiles + 1 tail tile of 25 rows
#define TAIL_  25              // 1849 - 57*32
#define NSLOT_ 57              // float4 slots per (copy, channel): max m = 7+49
#define LDSF4_ (16 * NSLOT_)   // 4 copies * 4 channels * 57 = 912 float4 (14.6 KB)

__global__ __launch_bounds__(256) void unfold_phase(const float* __restrict__ x,
                                                    float* __restrict__ out)
{
    __shared__ float4 lds[LDSF4_];

    unsigned int blk = blockIdx.x;
    unsigned int b   = blk / NT_;
    unsigned int t   = blk - b * NT_;
    unsigned int p0  = t * TP_;
    unsigned int rows = (t == NT_ - 1) ? TAIL_ : TP_;

    // ---- Stage: task tau = (c, m). Load x[c][p0+4m .. +7], emit 4 shifted copies.
    unsigned int tau = threadIdx.x;
    if (tau < 4u * NSLOT_) {
        unsigned int c = tau / NSLOT_;
        unsigned int m = tau - c * NSLOT_;
        const float* row = x + (size_t)(b * 4u + c) * L_;
        unsigned int g = p0 + 4u * m;
        float v0x, v0y, v0z, v0w, v1x, v1y, v1z;
        if (g + 7u <= (unsigned)(L_ - 1)) {
            float4 v0 = *reinterpret_cast<const float4*>(row + g);
            float4 v1 = *reinterpret_cast<const float4*>(row + g + 4);
            v0x = v0.x; v0y = v0.y; v0z = v0.z; v0w = v0.w;
            v1x = v1.x; v1y = v1.y; v1z = v1.z;
        } else {
            // tail tile: clamped scalar loads (values land in never-read slots)
            v0x = row[min(g + 0u, 2047u)];
            v0y = row[min(g + 1u, 2047u)];
            v0z = row[min(g + 2u, 2047u)];
            v0w = row[min(g + 3u, 2047u)];
            v1x = row[min(g + 4u, 2047u)];
            v1y = row[min(g + 5u, 2047u)];
            v1z = row[min(g + 6u, 2047u)];
        }
        lds[(0u * 4u + c) * NSLOT_ + m] = make_float4(v0x, v0y, v0z, v0w);
        lds[(1u * 4u + c) * NSLOT_ + m] = make_float4(v0y, v0z, v0w, v1x);
        lds[(2u * 4u + c) * NSLOT_ + m] = make_float4(v0z, v0w, v1x, v1y);
        lds[(3u * 4u + c) * NSLOT_ + m] = make_float4(v0w, v1x, v1y, v1z);
    }
    __syncthreads();

    // ---- Store: i = ((p*4 + c)*50 + k4), consecutive lanes -> consecutive i.
    float4* out4 = reinterpret_cast<float4*>(out) + (size_t)(b * LP_ + p0) * 200u;
    unsigned int i = threadIdx.x;
    unsigned int p = i / 200u;            // 0 or 1
    unsigned int r = i - p * 200u;

    if (rows == TP_) {
        // full tile: 32*200 = 6400 float4 = exactly 25 wave-256 iterations
#pragma unroll 5
        for (int n = 0; n < 25; ++n) {
            unsigned int c   = r / 50u;
            unsigned int k4  = r - c * 50u;
            unsigned int phi = p & 3u;
            unsigned int m   = (p >> 2u) + k4;
            out4[i] = lds[(phi * 4u + c) * NSLOT_ + m];
            i += 256u;
            unsigned int r2 = r + 56u;
            unsigned int w  = (r2 >= 200u) ? 1u : 0u;
            r = r2 - 200u * w;
            p += 1u + w;
        }
    } else {
        unsigned int n4 = rows * 200u;    // 5000
        for (; i < n4; i += 256u) {
            unsigned int c   = r / 50u;
            unsigned int k4  = r - c * 50u;
            unsigned int phi = p & 3u;
            unsigned int m   = (p >> 2u) + k4;
            out4[i] = lds[(phi * 4u + c) * NSLOT_ + m];
            unsigned int r2 = r + 56u;
            unsigned int w  = (r2 >= 200u) ? 1u : 0u;
            r = r2 - 200u * w;
            p += 1u + w;
        }
    }
}

extern "C" void kernel_launch(void* const* d_in, const int* in_sizes, int n_in,
                              void* d_out, int out_size, void* d_ws, size_t ws_size,
                              hipStream_t stream)
{
    const float* x = (const float*)d_in[0];
    float* out = (float*)d_out;

    int grid = B_ * NT_;   // 7424 blocks, each writes 102.4 KB contiguous
    unfold_phase<<<grid, 256, 0, stream>>>(x, out);
}